// Round 4
// baseline (205.508 us; speedup 1.0000x reference)
//
#include <hip/hip_runtime.h>
#include <math.h>

typedef _Float16 h8 __attribute__((ext_vector_type(8)));
typedef _Float16 h4 __attribute__((ext_vector_type(4)));
typedef float    f4 __attribute__((ext_vector_type(4)));

#define SAMPLES 64
#define HIDDEN  256

// d_ws layout (units: _Float16). Weights pre-split hi/lo, A-fragment order
// for the SWAPPED orientation: A = W^T, i.e. ws[(kg*16+ct)*64+lane][j] =
// W[kg*32+(lane>>4)*8+j][ct*16+(lane&15)].
#define OFF_W0HI 0            // [2][16][64][8]  = 16384 halfs
#define OFF_W0LO 16384
#define OFF_W1HI 32768        // [8][16][64][8]  = 65536
#define OFF_W1LO 98304
#define OFF_W2HI 163840
#define OFF_W2LO 229376
#define OFF_W3HI 294912       // [8][64][8] = 4096 (W3 cols padded 4->16)
#define OFF_W3LO 299008
// total 303104 halfs = 606 KB

__global__ void prep_weights(const float* __restrict__ W0,
                             const float* __restrict__ W1,
                             const float* __restrict__ W2,
                             const float* __restrict__ W3,
                             _Float16* __restrict__ ws)
{
    int id = blockIdx.x * blockDim.x + threadIdx.x;
    const int S0 = 64*256, S1 = 256*256;      // padded source grids
    const float* src; int hioff, looff, k, col, kmax, colmax, wide;
    if (id < S0)                { src=W0; hioff=OFF_W0HI; looff=OFF_W0LO; k=id>>8;  col=id&255; kmax=63;  colmax=256; wide=1; }
    else if (id < S0+S1)        { int t=id-S0;      src=W1; hioff=OFF_W1HI; looff=OFF_W1LO; k=t>>8; col=t&255; kmax=256; colmax=256; wide=1; }
    else if (id < S0+2*S1)      { int t=id-S0-S1;   src=W2; hioff=OFF_W2HI; looff=OFF_W2LO; k=t>>8; col=t&255; kmax=256; colmax=256; wide=1; }
    else if (id < S0+2*S1+4096) { int t=id-S0-2*S1; src=W3; hioff=OFF_W3HI; looff=OFF_W3LO; k=t>>4; col=t&15;  kmax=256; colmax=4;   wide=0; }
    else return;

    float v = (k < kmax && col < colmax) ? src[k*colmax + col] : 0.0f;
    _Float16 h = (_Float16)v;
    _Float16 l = (_Float16)(v - (float)h);

    int kg = k >> 5;
    int ln = (col & 15) | (((k >> 3) & 3) << 4);
    int j  = k & 7;
    int didx = wide ? (((kg*16 + (col >> 4))*64 + ln)*8 + j)
                    : ((kg*64 + ln)*8 + j);
    ws[hioff + didx] = h;
    ws[looff + didx] = l;
}

__device__ __forceinline__ f4 mfma3(h8 ahi, h8 alo, h8 bhi, h8 blo, f4 c)
{
    c = __builtin_amdgcn_mfma_f32_16x16x32_f16(alo, bhi, c, 0, 0, 0);
    c = __builtin_amdgcn_mfma_f32_16x16x32_f16(ahi, blo, c, 0, 0, 0);
    c = __builtin_amdgcn_mfma_f32_16x16x32_f16(ahi, bhi, c, 0, 0, 0);
    return c;
}

// One dense layer, swapped orientation: D[ch][samp] = W^T @ H^T.
// Wave (csl, sh) computes channels csl*64..+63 x samples sh*32..+31.
// Writeback: relu + hi/lo split into next layer's B-frag layout, one
// ds_write_b64 per tile per array.
template<int NKG>
__device__ __forceinline__ void dense_layer(const _Float16* __restrict__ Whi,
                                            const _Float16* __restrict__ Wlo,
                                            const float*    __restrict__ bias,
                                            _Float16* Bhi, _Float16* Blo,
                                            int csl, int sh, int lane)
{
    const int q  = lane >> 4;
    const int jl = lane & 15;
    f4 acc[4][2];
#pragma unroll
    for (int cht = 0; cht < 4; ++cht) {
        f4 bb = ((const f4*)(bias + csl*64 + cht*16))[q];   // acc row r -> ch q*4+r
        acc[cht][0] = bb;
        acc[cht][1] = bb;
    }
    const h8* wh  = (const h8*)Whi;
    const h8* wl  = (const h8*)Wlo;
    const h8* bhp = (const h8*)Bhi;
    const h8* blp = (const h8*)Blo;

    for (int kg = 0; kg < NKG; ++kg) {
        h8 ah[4], al[4], bh[2], bl[2];
#pragma unroll
        for (int cht = 0; cht < 4; ++cht) {
            int wi = (kg*16 + csl*4 + cht)*64 + lane;   // coalesced 16 B/lane, L2-hot
            ah[cht] = wh[wi];
            al[cht] = wl[wi];
        }
#pragma unroll
        for (int s2 = 0; s2 < 2; ++s2) {
            int bi = (kg*4 + sh*2 + s2)*64 + lane;      // ds_read_b128, conflict-free
            bh[s2] = bhp[bi];
            bl[s2] = blp[bi];
        }
#pragma unroll
        for (int cht = 0; cht < 4; ++cht)
#pragma unroll
            for (int s2 = 0; s2 < 2; ++s2)
                acc[cht][s2] = mfma3(ah[cht], al[cht], bh[s2], bl[s2], acc[cht][s2]);
    }

    __syncthreads();   // all waves done reading before in-place overwrite

#pragma unroll
    for (int cht = 0; cht < 4; ++cht) {
        // ch = csl*64 + cht*16 + q*4 + r  -> next-layer k
        int kgp = csl*2 + (cht >> 1);
        int lnp = jl + 16*(2*(cht & 1) + (q >> 1));
        int jb  = 4*(q & 1);
#pragma unroll
        for (int s2 = 0; s2 < 2; ++s2) {
            int st = sh*2 + s2;
            h4 vh, vl;
#pragma unroll
            for (int r = 0; r < 4; ++r) {
                float v = fmaxf(acc[cht][s2][r], 0.0f);
                _Float16 hh = (_Float16)v;
                vh[r] = hh;
                vl[r] = (_Float16)(v - (float)hh);
            }
            int base = ((kgp*4 + st)*64 + lnp)*8 + jb;
            *(h4*)(Bhi + base) = vh;
            *(h4*)(Blo + base) = vl;
        }
    }
    __syncthreads();
}

__launch_bounds__(512, 4)
__global__ void nerf_fused(const float* __restrict__ origins,
                           const float* __restrict__ dirs,
                           const float* __restrict__ nearp,
                           const float* __restrict__ farp,
                           const float* __restrict__ b0,
                           const float* __restrict__ b1,
                           const float* __restrict__ b2,
                           const float* __restrict__ b3,
                           const _Float16* __restrict__ ws,
                           float* __restrict__ out)
{
    extern __shared__ _Float16 sm[];
    _Float16* Bhi = sm;            // [8kg][4st][64lane][8] = 16384 halfs = 32 KB
    _Float16* Blo = sm + 16384;    // 32 KB (total 64 KB -> 2 blocks/CU, 16 waves)

    const int tid  = threadIdx.x;
    const int wv   = tid >> 6;
    const int lane = tid & 63;
    const int csl  = wv >> 1;      // channel slice 0..3
    const int sh   = wv & 1;       // sample half 0..1
    const int ray  = blockIdx.x;

    const float near = nearp[0];
    const float far  = farp[0];
    const float step = (far - near) * (1.0f / 64.0f);

    const float ox = origins[ray*3+0], oy = origins[ray*3+1], oz = origins[ray*3+2];
    const float dx = dirs[ray*3+0],    dy = dirs[ray*3+1],    dz = dirs[ray*3+2];

    // ---- PE directly into B-frag layout (K padded 63->64): one h8 per thread
    {
        int b  = tid;                    // = (kg*4+st)*64 + ln
        int ln = b & 63;
        int sample = ((b >> 6) & 3)*16 + (ln & 15);
        int k0 = (b >> 8)*32 + ((ln >> 4) << 3);
        float mid = (near + (float)sample*step) + (near + (float)(sample+1)*step)*0.5f;
        float c3[3] = { ox + mid*dx, oy + mid*dy, oz + mid*dz };
        h8 vh, vl;
#pragma unroll
        for (int j = 0; j < 8; ++j) {
            int k = k0 + j;
            float v;
            if (k < 3) v = c3[k];
            else if (k < 63) {
                int t = k - 3, l = t/6, r = t%6, d = r%3;
                float a = c3[d] * (float)(1 << l);
                v = (r < 3) ? sinf(a) : cosf(a);
            } else v = 0.0f;
            _Float16 hh = (_Float16)v;
            vh[j] = hh;
            vl[j] = (_Float16)(v - (float)hh);
        }
        ((h8*)Bhi)[b] = vh;
        ((h8*)Blo)[b] = vl;
    }
    __syncthreads();

    dense_layer<2>(ws+OFF_W0HI, ws+OFF_W0LO, b0, Bhi, Blo, csl, sh, lane);
    dense_layer<8>(ws+OFF_W1HI, ws+OFF_W1LO, b1, Bhi, Blo, csl, sh, lane);
    dense_layer<8>(ws+OFF_W2HI, ws+OFF_W2LO, b2, Bhi, Blo, csl, sh, lane);

    // ---- head: D[16pad ch][64 samp], K split across 8 waves (kg = wv)
    f4 hacc[4];
#pragma unroll
    for (int st = 0; st < 4; ++st) hacc[st] = (f4){0.f, 0.f, 0.f, 0.f};
    {
        h8 ah = ((const h8*)(ws+OFF_W3HI))[wv*64 + lane];
        h8 al = ((const h8*)(ws+OFF_W3LO))[wv*64 + lane];
        const h8* bhp = (const h8*)Bhi;
        const h8* blp = (const h8*)Blo;
#pragma unroll
        for (int st = 0; st < 4; ++st) {
            int bi = (wv*4 + st)*64 + lane;
            hacc[st] = mfma3(ah, al, bhp[bi], blp[bi], hacc[st]);
        }
    }
    __syncthreads();                       // B reads done -> safe to alias

    f4* part = (f4*)sm;                    // [wv][st][lane] f4 = 32 KB (Bhi region)
#pragma unroll
    for (int st = 0; st < 4; ++st) part[(wv*4 + st)*64 + lane] = hacc[st];
    __syncthreads();

    float* headv = (float*)(sm + 16384);   // [64 samp][4] f32 = 1 KB (Blo region)
    if (tid < 256) {
        int st = tid >> 6, l = tid & 63;
        f4 s = part[(0*4 + st)*64 + l];
#pragma unroll
        for (int w = 1; w < 8; ++w) s += part[(w*4 + st)*64 + l];
        int q = l >> 4, jl = l & 15;
        if (q == 0) {                      // rows 0..3 = the real 4 channels
            s += *(const f4*)b3;
            ((f4*)headv)[st*16 + jl] = s;  // [sample] -> (r,g,b,sigma)
        }
    }
    __syncthreads();

    // ---- compositing: wave 0, lane = sample
    if (tid < 64) {
        f4 f = ((const f4*)headv)[tid];
        const int p = tid;
        float sigma = fmaxf(f[3], 0.0f);
        float delta = (near + (float)(p + 1)*step) - (near + (float)p*step);
        float alpha = 1.0f - expf(-sigma * delta);
        float om    = 1.0f - alpha;

        float prod = om;
#pragma unroll
        for (int off = 1; off < 64; off <<= 1) {
            float v = __shfl_up(prod, off, 64);
            if (p >= off) prod *= v;
        }
        float T = __shfl_up(prod, 1, 64);
        if (p == 0) T = 1.0f;
        float w = T * alpha;

        float r  = w * (1.0f / (1.0f + expf(-f[0])));
        float g  = w * (1.0f / (1.0f + expf(-f[1])));
        float bb = w * (1.0f / (1.0f + expf(-f[2])));
#pragma unroll
        for (int off = 32; off > 0; off >>= 1) {
            r  += __shfl_down(r,  off, 64);
            g  += __shfl_down(g,  off, 64);
            bb += __shfl_down(bb, off, 64);
        }
        if (p == 0) {
            out[ray*3 + 0] = r;
            out[ray*3 + 1] = g;
            out[ray*3 + 2] = bb;
        }
    }
}

extern "C" void kernel_launch(void* const* d_in, const int* in_sizes, int n_in,
                              void* d_out, int out_size, void* d_ws, size_t ws_size,
                              hipStream_t stream) {
    const float* origins = (const float*)d_in[0];
    const float* dirs    = (const float*)d_in[1];
    const float* nearp   = (const float*)d_in[2];
    const float* farp    = (const float*)d_in[3];
    const float* W0      = (const float*)d_in[4];
    const float* b0      = (const float*)d_in[5];
    const float* W1      = (const float*)d_in[6];
    const float* b1      = (const float*)d_in[7];
    const float* W2      = (const float*)d_in[8];
    const float* b2      = (const float*)d_in[9];
    const float* W3      = (const float*)d_in[10];
    const float* b3      = (const float*)d_in[11];
    float* out           = (float*)d_out;
    _Float16* ws         = (_Float16*)d_ws;

    const int nrays = in_sizes[0] / 3;

    // source-driven, coalesced: 151552 threads, 1 load + 2 stores each
    prep_weights<<<dim3(592), dim3(256), 0, stream>>>(W0, W1, W2, W3, ws);

    const size_t shmem = 32768 * sizeof(_Float16);   // 64 KiB
    hipFuncSetAttribute(reinterpret_cast<const void*>(nerf_fused),
                        hipFuncAttributeMaxDynamicSharedMemorySize,
                        (int)shmem);
    nerf_fused<<<dim3(nrays), dim3(512), shmem, stream>>>(
        origins, dirs, nearp, farp, b0, b1, b2, b3, ws, out);
}